// Round 1
// baseline (115.843 us; speedup 1.0000x reference)
//
#include <hip/hip_runtime.h>
#include <math.h>

#define NB 512
#define HW 169
#define NA 5
#define NCH 125
#define BLOCK 256

__device__ __forceinline__ float sigmoidf_(float x) { return 1.0f / (1.0f + expf(-x)); }

__global__ __launch_bounds__(BLOCK) void yolo_loss_main(
    const float* __restrict__ P,   // [B][125][169] (channel-major)
    const float* __restrict__ T,   // [B][169][125]
    const float* __restrict__ ANC, // [5][2]
    double* __restrict__ partial,  // [5] f64 bins in ws
    int* __restrict__ coveredMask) // 1 int bitmask in ws
{
    int idx = blockIdx.x * BLOCK + threadIdx.x;   // grid exactly covers NB*HW
    int b  = idx / HW;
    int hw = idx - b * HW;

    const float* Pb = P + (size_t)b * NCH * HW + hw;
    const float* Tb = T + ((size_t)b * HW + hw) * NCH;

    float px[NA], py[NA], pw[NA], ph[NA];
    float gx[NA], gy[NA], gw_[NA], gh[NA], gc[NA];

#pragma unroll
    for (int a = 0; a < NA; ++a) {
        int c0 = a * 25;
        px[a] = sigmoidf_(Pb[(c0 + 21) * HW]);
        py[a] = sigmoidf_(Pb[(c0 + 22) * HW]);
        pw[a] = expf(Pb[(c0 + 23) * HW]);
        ph[a] = expf(Pb[(c0 + 24) * HW]);
        gc[a]  = Tb[c0 + 20];
        gx[a]  = Tb[c0 + 21];
        gy[a]  = Tb[c0 + 22];
        gw_[a] = Tb[c0 + 23];
        gh[a]  = Tb[c0 + 24];
    }

    float contrib[NA];
    int cmask = 0;
#pragma unroll
    for (int i = 0; i < NA; ++i) {
        float aw = ANC[2 * i], ah = ANC[2 * i + 1];
        float ax1 = px[i] - aw * 0.5f, ax2 = px[i] + aw * 0.5f;
        float ay1 = py[i] - ah * 0.5f, ay2 = py[i] + ah * 0.5f;
        float area_a = (ax2 - ax1) * (ay2 - ay1);
        float best = -1.0f; int bestj = 0;
#pragma unroll
        for (int j = 0; j < NA; ++j) {
            float bx1 = gx[j] - gw_[j] * 0.5f, bx2 = gx[j] + gw_[j] * 0.5f;
            float by1 = gy[j] - gh[j] * 0.5f, by2 = gy[j] + gh[j] * 0.5f;
            float iw = fmaxf(fminf(ax2, bx2) - fmaxf(ax1, bx1), 0.0f);
            float ih = fmaxf(fminf(ay2, by2) - fmaxf(ay1, by1), 0.0f);
            float inter = iw * ih;
            float area_b = (bx2 - bx1) * (by2 - by1);
            float iou = inter / (area_a + area_b - inter + 1e-10f);
            if (iou > best) { best = iou; bestj = j; }   // strict > == jnp.argmax first-max
        }
        cmask |= (1 << bestj);
        float dx = px[i] - gx[i], dy = py[i] - gy[i];
        float dw = pw[i] - gw_[i], dh = ph[i] - gh[i];
        contrib[i] = gc[i] * gc[i] * (dx * dx + dy * dy + dw * dw + dh * dh);
    }

    // wave-64 reduction per bin, then one f64 atomic per wave per bin
#pragma unroll
    for (int i = 0; i < NA; ++i) {
        float v = contrib[i];
        for (int off = 32; off; off >>= 1) v += __shfl_down(v, off, 64);
        if ((threadIdx.x & 63) == 0) atomicAdd(&partial[i], (double)v);
    }
    for (int off = 32; off; off >>= 1) cmask |= __shfl_down(cmask, off, 64);
    if ((threadIdx.x & 63) == 0) atomicOr(coveredMask, cmask);
}

__global__ void yolo_loss_final(const double* __restrict__ partial,
                                const int* __restrict__ coveredMask,
                                float* __restrict__ out)
{
    if (threadIdx.x == 0 && blockIdx.x == 0) {
        int m = *coveredMask;
        double s = 0.0;
        for (int a = 0; a < NA; ++a)
            if ((m >> a) & 1) s += partial[a];
        out[0] = (float)((5.0 / 512.0) * s);
    }
}

extern "C" void kernel_launch(void* const* d_in, const int* in_sizes, int n_in,
                              void* d_out, int out_size, void* d_ws, size_t ws_size,
                              hipStream_t stream) {
    const float* P   = (const float*)d_in[0];
    const float* T   = (const float*)d_in[1];
    const float* ANC = (const float*)d_in[2];
    float* out = (float*)d_out;

    double* partial = (double*)d_ws;          // 5 doubles
    int* coveredMask = (int*)(partial + NA);  // 1 int

    hipMemsetAsync(d_ws, 0, NA * sizeof(double) + sizeof(int), stream);

    int total = NB * HW;                       // 86528 = 338 * 256 exactly
    yolo_loss_main<<<total / BLOCK, BLOCK, 0, stream>>>(P, T, ANC, partial, coveredMask);
    yolo_loss_final<<<1, 64, 0, stream>>>(partial, coveredMask, out);
}

// Round 2
// 20.329 us; speedup vs baseline: 5.6984x; 5.6984x over previous
//
#include <hip/hip_runtime.h>
#include <math.h>

#define NB 512
#define HW 169
#define NA 5
#define NCH 125
#define BLOCK 256
#define NBLOCKS ((NB * HW) / BLOCK)   // 86528 / 256 = 338 exactly

__device__ __forceinline__ float sigmoidf_(float x) { return 1.0f / (1.0f + expf(-x)); }

__global__ __launch_bounds__(BLOCK) void yolo_loss_main(
    const float* __restrict__ P,    // [B][125][169] (channel-major)
    const float* __restrict__ T,    // [B][169][125]
    const float* __restrict__ ANC,  // [5][2]
    float* __restrict__ bsum,       // [NBLOCKS][5] per-block partial sums
    int* __restrict__ bmask)        // [NBLOCKS] per-block coverage bitmask
{
    int idx = blockIdx.x * BLOCK + threadIdx.x;
    int b  = idx / HW;
    int hw = idx - b * HW;

    const float* Pb = P + (size_t)b * NCH * HW + hw;
    const float* Tb = T + ((size_t)b * HW + hw) * NCH;

    float px[NA], py[NA], pw[NA], ph[NA];
    float gx[NA], gy[NA], gw_[NA], gh[NA], gc[NA];

#pragma unroll
    for (int a = 0; a < NA; ++a) {
        int c0 = a * 25;
        px[a] = sigmoidf_(Pb[(c0 + 21) * HW]);
        py[a] = sigmoidf_(Pb[(c0 + 22) * HW]);
        pw[a] = expf(Pb[(c0 + 23) * HW]);
        ph[a] = expf(Pb[(c0 + 24) * HW]);
        gc[a]  = Tb[c0 + 20];
        gx[a]  = Tb[c0 + 21];
        gy[a]  = Tb[c0 + 22];
        gw_[a] = Tb[c0 + 23];
        gh[a]  = Tb[c0 + 24];
    }

    float contrib[NA];
    int cmask = 0;
#pragma unroll
    for (int i = 0; i < NA; ++i) {
        float aw = ANC[2 * i], ah = ANC[2 * i + 1];
        float ax1 = px[i] - aw * 0.5f, ax2 = px[i] + aw * 0.5f;
        float ay1 = py[i] - ah * 0.5f, ay2 = py[i] + ah * 0.5f;
        float area_a = (ax2 - ax1) * (ay2 - ay1);
        float best = -1.0f; int bestj = 0;
#pragma unroll
        for (int j = 0; j < NA; ++j) {
            float bx1 = gx[j] - gw_[j] * 0.5f, bx2 = gx[j] + gw_[j] * 0.5f;
            float by1 = gy[j] - gh[j] * 0.5f, by2 = gy[j] + gh[j] * 0.5f;
            float iw = fmaxf(fminf(ax2, bx2) - fmaxf(ax1, bx1), 0.0f);
            float ih = fmaxf(fminf(ay2, by2) - fmaxf(ay1, by1), 0.0f);
            float inter = iw * ih;
            float area_b = (bx2 - bx1) * (by2 - by1);
            float iou = inter / (area_a + area_b - inter + 1e-10f);
            if (iou > best) { best = iou; bestj = j; }   // strict > == jnp.argmax first-max
        }
        cmask |= (1 << bestj);
        float dx = px[i] - gx[i], dy = py[i] - gy[i];
        float dw = pw[i] - gw_[i], dh = ph[i] - gh[i];
        contrib[i] = gc[i] * gc[i] * (dx * dx + dy * dy + dw * dw + dh * dh);
    }

    // wave-64 shuffle reduce, then cross-wave via LDS, one global write per block
    __shared__ float sred[4][NA];
    __shared__ int smask[4];
    int lane = threadIdx.x & 63, wid = threadIdx.x >> 6;

#pragma unroll
    for (int i = 0; i < NA; ++i) {
        float v = contrib[i];
        for (int off = 32; off; off >>= 1) v += __shfl_down(v, off, 64);
        if (lane == 0) sred[wid][i] = v;
    }
    for (int off = 32; off; off >>= 1) cmask |= __shfl_down(cmask, off, 64);
    if (lane == 0) smask[wid] = cmask;
    __syncthreads();

    if (threadIdx.x == 0) {
        int m = smask[0] | smask[1] | smask[2] | smask[3];
#pragma unroll
        for (int i = 0; i < NA; ++i)
            bsum[blockIdx.x * NA + i] = sred[0][i] + sred[1][i] + sred[2][i] + sred[3][i];
        bmask[blockIdx.x] = m;
    }
}

__global__ void yolo_loss_final(const float* __restrict__ bsum,
                                const int* __restrict__ bmask,
                                float* __restrict__ out)
{
    int lane = threadIdx.x;          // one 64-lane wave
    double s[NA] = {0, 0, 0, 0, 0};
    int m = 0;
    for (int e = lane; e < NBLOCKS; e += 64) {
#pragma unroll
        for (int i = 0; i < NA; ++i) s[i] += (double)bsum[e * NA + i];
        m |= bmask[e];
    }
#pragma unroll
    for (int i = 0; i < NA; ++i)
        for (int off = 32; off; off >>= 1) s[i] += __shfl_down(s[i], off, 64);
    for (int off = 32; off; off >>= 1) m |= __shfl_down(m, off, 64);

    if (lane == 0) {
        double tot = 0.0;
#pragma unroll
        for (int i = 0; i < NA; ++i)
            if ((m >> i) & 1) tot += s[i];
        out[0] = (float)((5.0 / 512.0) * tot);
    }
}

extern "C" void kernel_launch(void* const* d_in, const int* in_sizes, int n_in,
                              void* d_out, int out_size, void* d_ws, size_t ws_size,
                              hipStream_t stream) {
    const float* P   = (const float*)d_in[0];
    const float* T   = (const float*)d_in[1];
    const float* ANC = (const float*)d_in[2];
    float* out = (float*)d_out;

    float* bsum = (float*)d_ws;                 // NBLOCKS * 5 floats
    int* bmask  = (int*)(bsum + NBLOCKS * NA);  // NBLOCKS ints

    yolo_loss_main<<<NBLOCKS, BLOCK, 0, stream>>>(P, T, ANC, bsum, bmask);
    yolo_loss_final<<<1, 64, 0, stream>>>(bsum, bmask, out);
}

// Round 3
// 20.169 us; speedup vs baseline: 5.7435x; 1.0079x over previous
//
#include <hip/hip_runtime.h>
#include <math.h>

#define NB 512
#define HW 169
#define NA 5
#define NCH 125
#define BLOCK 256
#define NBLOCKS ((NB * HW) / BLOCK)   // 86528 / 256 = 338 exactly
#define REC 8                          // padded per-block record (dwords)

__global__ __launch_bounds__(BLOCK, 2) void yolo_loss_main(
    const float* __restrict__ P,    // [B][125][169] (channel-major)
    const float* __restrict__ T,    // [B][169][125]
    const float* __restrict__ ANC,  // [5][2]
    float* __restrict__ brec)       // [NBLOCKS][REC]: sums[5], mask, pad[2]
{
    int idx = blockIdx.x * BLOCK + threadIdx.x;
    int b  = idx / HW;
    int hw = idx - b * HW;

    const float* Pb = P + (size_t)b * NCH * HW + hw;
    const float* Tb = T + ((size_t)b * HW + hw) * NCH;

    // ---- phase 1: issue ALL 45 loads as raw values (no transcendentals in between)
    float rx[NA], ry[NA], rw[NA], rh[NA];           // raw prediction logits
    float gx[NA], gy[NA], gw_[NA], gh[NA], gc[NA];  // gt box + conf
#pragma unroll
    for (int a = 0; a < NA; ++a) {
        int c0 = a * 25;
        rx[a] = Pb[(c0 + 21) * HW];
        ry[a] = Pb[(c0 + 22) * HW];
        rw[a] = Pb[(c0 + 23) * HW];
        rh[a] = Pb[(c0 + 24) * HW];
    }
#pragma unroll
    for (int a = 0; a < NA; ++a) {
        int c0 = a * 25;
        gc[a]  = Tb[c0 + 20];
        gx[a]  = Tb[c0 + 21];
        gy[a]  = Tb[c0 + 22];
        gw_[a] = Tb[c0 + 23];
        gh[a]  = Tb[c0 + 24];
    }

    // ---- phase 2: transforms
    float px[NA], py[NA], pw[NA], ph[NA];
#pragma unroll
    for (int a = 0; a < NA; ++a) {
        px[a] = 1.0f / (1.0f + expf(-rx[a]));
        py[a] = 1.0f / (1.0f + expf(-ry[a]));
        pw[a] = expf(rw[a]);
        ph[a] = expf(rh[a]);
    }

    float contrib[NA];
    int cmask = 0;
#pragma unroll
    for (int i = 0; i < NA; ++i) {
        float aw = ANC[2 * i], ah = ANC[2 * i + 1];
        float ax1 = px[i] - aw * 0.5f, ax2 = px[i] + aw * 0.5f;
        float ay1 = py[i] - ah * 0.5f, ay2 = py[i] + ah * 0.5f;
        float area_a = (ax2 - ax1) * (ay2 - ay1);
        float best = -1.0f; int bestj = 0;
#pragma unroll
        for (int j = 0; j < NA; ++j) {
            float bx1 = gx[j] - gw_[j] * 0.5f, bx2 = gx[j] + gw_[j] * 0.5f;
            float by1 = gy[j] - gh[j] * 0.5f, by2 = gy[j] + gh[j] * 0.5f;
            float iw = fmaxf(fminf(ax2, bx2) - fmaxf(ax1, bx1), 0.0f);
            float ih = fmaxf(fminf(ay2, by2) - fmaxf(ay1, by1), 0.0f);
            float inter = iw * ih;
            float area_b = (bx2 - bx1) * (by2 - by1);
            float iou = inter / (area_a + area_b - inter + 1e-10f);
            if (iou > best) { best = iou; bestj = j; }   // strict > == jnp.argmax first-max
        }
        cmask |= (1 << bestj);
        float dx = px[i] - gx[i], dy = py[i] - gy[i];
        float dw = pw[i] - gw_[i], dh = ph[i] - gh[i];
        contrib[i] = gc[i] * gc[i] * (dx * dx + dy * dy + dw * dw + dh * dh);
    }

    // ---- phase 3: wave shuffle reduce -> LDS cross-wave -> one 24B write per block
    __shared__ float sred[4][NA];
    __shared__ int smask[4];
    int lane = threadIdx.x & 63, wid = threadIdx.x >> 6;

#pragma unroll
    for (int i = 0; i < NA; ++i) {
        float v = contrib[i];
        for (int off = 32; off; off >>= 1) v += __shfl_down(v, off, 64);
        if (lane == 0) sred[wid][i] = v;
    }
    for (int off = 32; off; off >>= 1) cmask |= __shfl_down(cmask, off, 64);
    if (lane == 0) smask[wid] = cmask;
    __syncthreads();

    if (threadIdx.x == 0) {
        int m = smask[0] | smask[1] | smask[2] | smask[3];
        float* r = brec + blockIdx.x * REC;
#pragma unroll
        for (int i = 0; i < NA; ++i)
            r[i] = sred[0][i] + sred[1][i] + sred[2][i] + sred[3][i];
        ((int*)r)[5] = m;
    }
}

__global__ void yolo_loss_final(const float* __restrict__ brec,
                                float* __restrict__ out)
{
    int lane = threadIdx.x;          // one 64-lane wave
    double s[NA] = {0, 0, 0, 0, 0};
    int m = 0;
    for (int e = lane; e < NBLOCKS; e += 64) {
        const float* r = brec + e * REC;
#pragma unroll
        for (int i = 0; i < NA; ++i) s[i] += (double)r[i];
        m |= ((const int*)r)[5];
    }
#pragma unroll
    for (int i = 0; i < NA; ++i)
        for (int off = 32; off; off >>= 1) s[i] += __shfl_down(s[i], off, 64);
    for (int off = 32; off; off >>= 1) m |= __shfl_down(m, off, 64);

    if (lane == 0) {
        double tot = 0.0;
#pragma unroll
        for (int i = 0; i < NA; ++i)
            if ((m >> i) & 1) tot += s[i];
        out[0] = (float)((5.0 / 512.0) * tot);
    }
}

extern "C" void kernel_launch(void* const* d_in, const int* in_sizes, int n_in,
                              void* d_out, int out_size, void* d_ws, size_t ws_size,
                              hipStream_t stream) {
    const float* P   = (const float*)d_in[0];
    const float* T   = (const float*)d_in[1];
    const float* ANC = (const float*)d_in[2];
    float* out = (float*)d_out;

    float* brec = (float*)d_ws;   // NBLOCKS * REC floats

    yolo_loss_main<<<NBLOCKS, BLOCK, 0, stream>>>(P, T, ANC, brec);
    yolo_loss_final<<<1, 64, 0, stream>>>(brec, out);
}